// Round 15
// baseline (255.261 us; speedup 1.0000x reference)
//
#include <hip/hip_runtime.h>

// ---------------------------------------------------------------------------
// GIN 2-layer forward. R25: R24 hybrid + PAIR-INTERLEAVED gather in
// fused_layer phase A. Fused kernel runs 16 waves/CU (vs standalone agg's
// 32), so per-wave outstanding loads double: each lane-group processes its
// 4 nodes as 2 pairs, issuing both nodes' 8-edge batches jointly -> 16
// row-loads in flight/lane (was 8). Degree mismatch via sel-mask (dup last
// edge, L1-hot, x0). VGPR 52 -> ~90 (headroom: 4 waves/SIMD allows 128).
// 5 dispatches: memset, prep_fill, agg16, mlp0, fused1.
// N=50000, E=600000, dims 128->256->256->256->128.
// ---------------------------------------------------------------------------

typedef __bf16 bf16x8 __attribute__((ext_vector_type(8)));
typedef float f32x4 __attribute__((ext_vector_type(4)));
typedef float f32x2 __attribute__((ext_vector_type(2)));
typedef unsigned short u16x4 __attribute__((ext_vector_type(4)));
typedef unsigned short u16x8 __attribute__((ext_vector_type(8)));
typedef unsigned int uint32;
typedef uint32 u32x4 __attribute__((ext_vector_type(4)));

#define MAXDEG 48

__device__ __forceinline__ unsigned short f2bf(float f) {
  uint32 u = __builtin_bit_cast(uint32, f);
  u += 0x7FFFu + ((u >> 16) & 1u);  // RNE
  return (unsigned short)(u >> 16);
}
// two bf16 (packed in a u32) -> two f32: lo via shift, hi via mask (1 instr each)
__device__ __forceinline__ f32x2 bfpair(uint32 w) {
  f32x2 r;
  r.x = __builtin_bit_cast(float, w << 16);
  r.y = __builtin_bit_cast(float, w & 0xFFFF0000u);
  return r;
}

#define G2L16(gp, lp)                                                        \
  __builtin_amdgcn_global_load_lds(                                          \
      (const __attribute__((address_space(1))) void*)(gp),                   \
      (__attribute__((address_space(3))) void*)(lp), 16, 0, 0)

// raw barrier with compiler-level memory fences; data readiness enforced by
// the explicit vmcnt
#define BARRIER()                                                            \
  do {                                                                       \
    asm volatile("" ::: "memory");                                           \
    __builtin_amdgcn_s_barrier();                                            \
    asm volatile("" ::: "memory");                                           \
  } while (0)
#define VMCNT0() asm volatile("s_waitcnt vmcnt(0)" ::: "memory")

// ---------------- merged prep + ELL fill (R21) ------------------------------
__global__ __launch_bounds__(256) void prep_fill(
    const int* __restrict__ eidx, int* __restrict__ deg, int* __restrict__ ell,
    int E, int FB,
    const float* __restrict__ x, unsigned short* __restrict__ xb, long long n4,
    const float* __restrict__ W1a, const float* __restrict__ W2a,
    const float* __restrict__ W1b, const float* __restrict__ W2b,
    unsigned short* __restrict__ w1t, unsigned short* __restrict__ w2t,
    unsigned short* __restrict__ w3t, unsigned short* __restrict__ w4t) {
  int b = blockIdx.x;
  int t = threadIdx.x;
  if (b < FB) {
    int e = b * 256 + t;
    if (e < E) {
      int s = eidx[e];
      int d = eidx[e + E];
      int c = atomicAdd(&deg[d], 1);
      if (c < MAXDEG) ell[d * MAXDEG + c] = s;
    }
  } else if (b < FB + 768) {
    int i = (b - FB) * 256 + t;  // 0..196607
    const float* W;
    unsigned short* WT;
    int K, N, j;
    if (i < 32768) {            // W1a: 128x256
      W = W1a; WT = w1t; K = 128; N = 256; j = i;
    } else if (i < 98304) {     // W2a: 256x256
      W = W2a; WT = w2t; K = 256; N = 256; j = i - 32768;
    } else if (i < 163840) {    // W1b: 256x256
      W = W1b; WT = w3t; K = 256; N = 256; j = i - 98304;
    } else {                    // W2b: 256x128
      W = W2b; WT = w4t; K = 256; N = 128; j = i - 163840;
    }
    int k = j / N, n = j - k * N;
    WT[n * K + k] = f2bf(W[j]);
  } else {
    long long i = (long long)(b - FB - 768) * 256 + t;
    long long stride = (long long)(gridDim.x - FB - 768) * 256;
    for (; i < n4; i += stride) {
      float4 v = ((const float4*)x)[i];
      u16x4 o;
      o.x = f2bf(v.x); o.y = f2bf(v.y); o.z = f2bf(v.z); o.w = f2bf(v.w);
      ((u16x4*)xb)[i] = o;
    }
  }
}

// ------------------------- aggregation (ELL, R19) ---------------------------
template <int GRP>  // D = GRP*8 dims: GRP=16 -> D=128
__global__ __launch_bounds__(256) void agg_gather(
    unsigned short* __restrict__ out, const unsigned short* __restrict__ src,
    const int* __restrict__ degv, const int* __restrict__ ell, int Nn) {
  constexpr int RS = GRP * 8;        // row stride in shorts (= D)
  constexpr int GPB = 256 / GRP;     // node-groups per block
  const int gid = threadIdx.x / GRP;
  const int gl  = threadIdx.x % GRP;
  const unsigned short* sp = src + gl * 8;
  const int stride = gridDim.x * GPB;
  for (int node = blockIdx.x * GPB + gid; node < Nn; node += stride) {
    const int beg = node * MAXDEG;
    int deg = degv[node];
    if (deg > MAXDEG) deg = MAXDEG;
    f32x2 acc[4];
    {  // self row ((1+eps)*x with eps=0)
      u32x4 w = *(const u32x4*)(sp + (size_t)node * RS);
#pragma unroll
      for (int k = 0; k < 4; ++k) acc[k] = bfpair(w[k]);
    }
    int j = 0;
    for (; j + 8 <= deg; j += 8) {  // full batches: no masking
      int idx[8];
#pragma unroll
      for (int u = 0; u < 8; ++u) idx[u] = ell[beg + j + u];
#pragma unroll
      for (int u = 0; u < 8; ++u) {
        u32x4 w = *(const u32x4*)(sp + (size_t)idx[u] * RS);
#pragma unroll
        for (int k = 0; k < 4; ++k) acc[k] += bfpair(w[k]);
      }
    }
    if (j < deg) {  // masked tail
#pragma unroll
      for (int u = 0; u < 8; ++u) {
        int jj = j + u;
        int e = beg + (jj < deg ? jj : deg - 1);
        float sel = (jj < deg) ? 1.f : 0.f;
        f32x2 fs = {sel, sel};
        int rv = ell[e];
        u32x4 w = *(const u32x4*)(sp + (size_t)rv * RS);
#pragma unroll
        for (int k = 0; k < 4; ++k) acc[k] += bfpair(w[k]) * fs;
      }
    }
    u16x8 o;
#pragma unroll
    for (int k = 0; k < 4; ++k) {
      o[2 * k] = f2bf(acc[k].x);
      o[2 * k + 1] = f2bf(acc[k].y);
    }
    *(u16x8*)(out + (size_t)node * RS + gl * 8) = o;
  }
}

// ------------- fused MLP, 8 waves, 2-phase dbuf pipeline (R20) ---------------
template <int K1, int N2, bool OUT_BF16>
__global__ __launch_bounds__(512) void fused_mlp8(
    const unsigned short* __restrict__ A,
    const unsigned short* __restrict__ BT1, const float* __restrict__ b1,
    const unsigned short* __restrict__ BT2, const float* __restrict__ b2,
    void* __restrict__ Cout, int M) {
  __shared__ unsigned short As[2][64 * 32];    // 8 KB
  __shared__ unsigned short Bs[2][256 * 32];   // 32 KB
  __shared__ unsigned short Ts[64 * 264];      // 33.8 KB
  const int tid = threadIdx.x;
  const int wave = tid >> 6, lane = tid & 63;
  const int quad = lane >> 4, l16 = lane & 15;
  const int rowBase = blockIdx.x * 64;

#define STAGE1(buf, kk)                                                      \
  for (int c = tid; c < 1280; c += 512) {                                    \
    if (c < 256) {                                                           \
      int r = rowBase + (c >> 2);                                            \
      if (r > M - 1) r = M - 1;                                              \
      G2L16(A + (long long)r * K1 + (kk) + (c & 3) * 8, As[buf] + c * 8);    \
    } else {                                                                 \
      int bb = c - 256;                                                      \
      G2L16(BT1 + (long long)(bb >> 2) * K1 + (kk) + (bb & 3) * 8,           \
            Bs[buf] + bb * 8);                                               \
    }                                                                        \
  }

  // ---- stage 1: T = relu(A @ W1 + b1); wave owns cols wave*32..+31 ----
  constexpr int nk1 = K1 / 32;
  f32x4 acc[4][2] = {};
  int cur = 0;
  STAGE1(0, 0);
  VMCNT0();
  BARRIER();
  for (int t = 0; t < nk1; ++t) {
    if (t + 1 < nk1) STAGE1(cur ^ 1, (t + 1) * 32);
    bf16x8 af[4], bfr[2];
#pragma unroll
    for (int mi = 0; mi < 4; ++mi)
      af[mi] = *(const bf16x8*)(As[cur] + (mi * 16 + l16) * 32 + quad * 8);
#pragma unroll
    for (int ni = 0; ni < 2; ++ni)
      bfr[ni] = *(const bf16x8*)(Bs[cur] + (wave * 32 + ni * 16 + l16) * 32 + quad * 8);
#pragma unroll
    for (int mi = 0; mi < 4; ++mi)
#pragma unroll
      for (int ni = 0; ni < 2; ++ni)
        acc[mi][ni] = __builtin_amdgcn_mfma_f32_16x16x32_bf16(
            af[mi], bfr[ni], acc[mi][ni], 0, 0, 0);
    VMCNT0();
    BARRIER();
    cur ^= 1;
  }
#pragma unroll
  for (int ni = 0; ni < 2; ++ni) {
    int col = wave * 32 + ni * 16 + l16;
    float bv = b1[col];
#pragma unroll
    for (int mi = 0; mi < 4; ++mi)
#pragma unroll
      for (int r = 0; r < 4; ++r) {
        int row = mi * 16 + quad * 4 + r;
        Ts[row * 264 + col] = f2bf(fmaxf(acc[mi][ni][r] + bv, 0.f));
      }
  }
  __syncthreads();

  // ---- stage 2: C = T @ W2 + b2; wave owns cols wave*(N2/8).. ----
  constexpr int NW2 = N2 / 8;
  constexpr int NI2 = NW2 / 16;
  constexpr int NCH2 = N2 * 4;

#define STAGE2(buf, kk)                                                      \
  for (int c = tid; c < NCH2; c += 512)                                      \
    G2L16(BT2 + (long long)(c >> 2) * 256 + (kk) + (c & 3) * 8,              \
          Bs[buf] + c * 8);

  f32x4 acc2[4][NI2] = {};
  cur = 0;
  STAGE2(0, 0);
  VMCNT0();
  BARRIER();
  for (int t = 0; t < 8; ++t) {
    int k2 = t * 32;
    if (t + 1 < 8) STAGE2(cur ^ 1, k2 + 32);
    bf16x8 af[4], bfr[NI2];
#pragma unroll
    for (int mi = 0; mi < 4; ++mi)
      af[mi] = *(const bf16x8*)(Ts + (mi * 16 + l16) * 264 + k2 + quad * 8);
#pragma unroll
    for (int ni = 0; ni < NI2; ++ni)
      bfr[ni] = *(const bf16x8*)(Bs[cur] + (wave * NW2 + ni * 16 + l16) * 32 + quad * 8);
#pragma unroll
    for (int mi = 0; mi < 4; ++mi)
#pragma unroll
      for (int ni = 0; ni < NI2; ++ni)
        acc2[mi][ni] = __builtin_amdgcn_mfma_f32_16x16x32_bf16(
            af[mi], bfr[ni], acc2[mi][ni], 0, 0, 0);
    VMCNT0();
    BARRIER();
    cur ^= 1;
  }
#pragma unroll
  for (int ni = 0; ni < NI2; ++ni) {
    int col = wave * NW2 + ni * 16 + l16;
    float bv = b2[col];
#pragma unroll
    for (int mi = 0; mi < 4; ++mi)
#pragma unroll
      for (int r = 0; r < 4; ++r) {
        int row = rowBase + mi * 16 + quad * 4 + r;
        if (row < M) {
          float o = acc2[mi][ni][r] + bv;
          if (OUT_BF16)
            ((unsigned short*)Cout)[(long long)row * N2 + col] = f2bf(fmaxf(o, 0.f));
          else
            ((float*)Cout)[(long long)row * N2 + col] = o;
        }
      }
  }
#undef STAGE1
#undef STAGE2
}

// -------- fused layer: pair-interleaved gather + 2-stage MLP (R25) ----------
template <int K1, int N2, bool OUT_BF16>
__global__ __launch_bounds__(512) void fused_layer(
    const unsigned short* __restrict__ src,   // gather table, row stride K1
    const int* __restrict__ degv, const int* __restrict__ ell,
    const unsigned short* __restrict__ BT1, const float* __restrict__ b1,
    const unsigned short* __restrict__ BT2, const float* __restrict__ b2,
    void* __restrict__ Cout, int Nn) {
  constexpr int GRP = K1 / 8;
  __shared__ unsigned short Ash[64 * 264];     // A-tile, then Ts (33.8 KB)
  __shared__ unsigned short Bs[2][256 * 32];   // 32 KB dbuf
  const int tid = threadIdx.x;
  const int wave = tid >> 6, lane = tid & 63;
  const int quad = lane >> 4, l16 = lane & 15;
  const int rowBase = blockIdx.x * 64;

#define STAGE1B(buf, kk)                                                     \
  for (int c = tid; c < 1024; c += 512)                                      \
    G2L16(BT1 + (long long)(c >> 2) * K1 + (kk) + (c & 3) * 8,               \
          Bs[buf] + c * 8);
#define STAGE2B(buf, kk)                                                     \
  for (int c = tid; c < N2 * 4; c += 512)                                    \
    G2L16(BT2 + (long long)(c >> 2) * 256 + (kk) + (c & 3) * 8,              \
          Bs[buf] + c * 8);

  // prologue: first B-tile flies under the gather
  STAGE1B(0, 0);

  // ---- phase A: pair-interleaved gather of this block's 64 rows ----
  {
    constexpr int NPG = 64 * GRP / 512;  // nodes per lane-group (4 @ K1=256)
    const int gid = tid / GRP, gl = tid % GRP;
    const unsigned short* sp = src + gl * 8;
#pragma unroll
    for (int p = 0; p < NPG; p += 2) {
      const int lrow0 = gid * NPG + p;
      int node0 = rowBase + lrow0;
      if (node0 > Nn - 1) node0 = Nn - 1;
      int node1 = rowBase + lrow0 + 1;
      if (node1 > Nn - 1) node1 = Nn - 1;
      const int beg0 = node0 * MAXDEG, beg1 = node1 * MAXDEG;
      int dg0 = degv[node0]; if (dg0 > MAXDEG) dg0 = MAXDEG;
      int dg1 = degv[node1]; if (dg1 > MAXDEG) dg1 = MAXDEG;
      const int dgm = dg0 > dg1 ? dg0 : dg1;
      f32x2 a0[4], a1[4];
      {  // both self rows issued together
        u32x4 w0 = *(const u32x4*)(sp + (size_t)node0 * K1);
        u32x4 w1 = *(const u32x4*)(sp + (size_t)node1 * K1);
#pragma unroll
        for (int k = 0; k < 4; ++k) {
          a0[k] = bfpair(w0[k]);
          a1[k] = bfpair(w1[k]);
        }
      }
      // joint masked batches: 16 row-loads in flight per lane
      for (int j = 0; j < dgm; j += 8) {
        int i0[8], i1[8];
#pragma unroll
        for (int u = 0; u < 8; ++u) {
          int jj = j + u;
          i0[u] = ell[beg0 + (jj < dg0 ? jj : dg0 - 1)];
          i1[u] = ell[beg1 + (jj < dg1 ? jj : dg1 - 1)];
        }
#pragma unroll
        for (int u = 0; u < 8; ++u) {
          int jj = j + u;
          float s0 = (jj < dg0) ? 1.f : 0.f;
          float s1 = (jj < dg1) ? 1.f : 0.f;
          f32x2 f0 = {s0, s0}, f1 = {s1, s1};
          u32x4 w0 = *(const u32x4*)(sp + (size_t)i0[u] * K1);
          u32x4 w1 = *(const u32x4*)(sp + (size_t)i1[u] * K1);
#pragma unroll
          for (int k = 0; k < 4; ++k) {
            a0[k] += bfpair(w0[k]) * f0;
            a1[k] += bfpair(w1[k]) * f1;
          }
        }
      }
      u16x8 o0, o1;
#pragma unroll
      for (int k = 0; k < 4; ++k) {
        o0[2 * k] = f2bf(a0[k].x); o0[2 * k + 1] = f2bf(a0[k].y);
        o1[2 * k] = f2bf(a1[k].x); o1[2 * k + 1] = f2bf(a1[k].y);
      }
      *(u16x8*)(Ash + lrow0 * 264 + gl * 8) = o0;
      *(u16x8*)(Ash + (lrow0 + 1) * 264 + gl * 8) = o1;
    }
  }
  __syncthreads();  // gather ds_writes + STAGE1B(0) drained

  // ---- stage 1: T = relu(A @ W1 + b1); wave owns cols wave*32..+31 ----
  constexpr int nk1 = K1 / 32;
  f32x4 acc1[4][2] = {};
  int cur = 0;
  for (int t = 0; t < nk1; ++t) {
    if (t + 1 < nk1) STAGE1B(cur ^ 1, (t + 1) * 32);
    bf16x8 af[4], bfr[2];
#pragma unroll
    for (int mi = 0; mi < 4; ++mi)
      af[mi] = *(const bf16x8*)(Ash + (mi * 16 + l16) * 264 + t * 32 + quad * 8);
#pragma unroll
    for (int ni = 0; ni < 2; ++ni)
      bfr[ni] = *(const bf16x8*)(Bs[cur] + (wave * 32 + ni * 16 + l16) * 32 + quad * 8);
#pragma unroll
    for (int mi = 0; mi < 4; ++mi)
#pragma unroll
      for (int ni = 0; ni < 2; ++ni)
        acc1[mi][ni] = __builtin_amdgcn_mfma_f32_16x16x32_bf16(
            af[mi], bfr[ni], acc1[mi][ni], 0, 0, 0);
    VMCNT0();
    BARRIER();
    cur ^= 1;
  }

  // stage-2 prologue hides under the Ts write
  STAGE2B(0, 0);
#pragma unroll
  for (int ni = 0; ni < 2; ++ni) {
    int col = wave * 32 + ni * 16 + l16;
    float bv = b1[col];
#pragma unroll
    for (int mi = 0; mi < 4; ++mi)
#pragma unroll
      for (int r = 0; r < 4; ++r) {
        int row = mi * 16 + quad * 4 + r;
        Ash[row * 264 + col] = f2bf(fmaxf(acc1[mi][ni][r] + bv, 0.f));
      }
  }
  __syncthreads();  // Ts writes + STAGE2B(0) drained

  // ---- stage 2: C = T @ W2 + b2; wave owns cols wave*(N2/8).. ----
  constexpr int NW2 = N2 / 8;
  constexpr int NI2 = NW2 / 16;
  f32x4 acc2[4][NI2] = {};
  cur = 0;
  for (int t = 0; t < 8; ++t) {
    int k2 = t * 32;
    if (t + 1 < 8) STAGE2B(cur ^ 1, k2 + 32);
    bf16x8 af[4], bfr[NI2];
#pragma unroll
    for (int mi = 0; mi < 4; ++mi)
      af[mi] = *(const bf16x8*)(Ash + (mi * 16 + l16) * 264 + k2 + quad * 8);
#pragma unroll
    for (int ni = 0; ni < NI2; ++ni)
      bfr[ni] = *(const bf16x8*)(Bs[cur] + (wave * NW2 + ni * 16 + l16) * 32 + quad * 8);
#pragma unroll
    for (int mi = 0; mi < 4; ++mi)
#pragma unroll
      for (int ni = 0; ni < NI2; ++ni)
        acc2[mi][ni] = __builtin_amdgcn_mfma_f32_16x16x32_bf16(
            af[mi], bfr[ni], acc2[mi][ni], 0, 0, 0);
    VMCNT0();
    BARRIER();
    cur ^= 1;
  }
#pragma unroll
  for (int ni = 0; ni < NI2; ++ni) {
    int col = wave * NW2 + ni * 16 + l16;
    float bv = b2[col];
#pragma unroll
    for (int mi = 0; mi < 4; ++mi)
#pragma unroll
      for (int r = 0; r < 4; ++r) {
        int row = rowBase + mi * 16 + quad * 4 + r;
        if (row < Nn) {
          float o = acc2[mi][ni][r] + bv;
          if (OUT_BF16)
            ((unsigned short*)Cout)[(long long)row * N2 + col] = f2bf(fmaxf(o, 0.f));
          else
            ((float*)Cout)[(long long)row * N2 + col] = o;
        }
      }
  }
#undef STAGE1B
#undef STAGE2B
}

// ---------------------------------------------------------------------------
extern "C" void kernel_launch(void* const* d_in, const int* in_sizes, int n_in,
                              void* d_out, int out_size, void* d_ws, size_t ws_size,
                              hipStream_t stream) {
  const float* x   = (const float*)d_in[0];
  const float* W1a = (const float*)d_in[1];
  const float* b1a = (const float*)d_in[2];
  const float* W2a = (const float*)d_in[3];
  const float* b2a = (const float*)d_in[4];
  const float* W1b = (const float*)d_in[5];
  const float* b1b = (const float*)d_in[6];
  const float* W2b = (const float*)d_in[7];
  const float* b2b = (const float*)d_in[8];
  const int*   ei  = (const int*)d_in[9];  // [2,E]: row0=src, row1=dst

  const int Nn = in_sizes[0] / 128;  // 50000
  const int E  = in_sizes[9] / 2;    // 600000
  float* out = (float*)d_out;

  // workspace
  unsigned short* h   = (unsigned short*)d_ws;     // N*256 bf16
  unsigned short* g0  = h  + (size_t)Nn * 256;     // N*128 (layer-0 agg out)
  unsigned short* xb  = g0 + (size_t)Nn * 128;     // N*128
  unsigned short* w1t = xb + (size_t)Nn * 128;     // 256*128
  unsigned short* w2t = w1t + 256 * 128;           // 256*256
  unsigned short* w3t = w2t + 256 * 256;           // 256*256
  unsigned short* w4t = w3t + 256 * 256;           // 128*256
  int* deg  = (int*)(w4t + 128 * 256);             // Nn (zeroed by memset)
  int* ell  = deg + Nn;                            // Nn*MAXDEG

  dim3 blk(256);
  const int FB = (E + 255) / 256;  // 2344 fill blocks

  // 1) zero deg (stream-ordered, graph-capturable)
  hipMemsetAsync(deg, 0, (size_t)Nn * sizeof(int), stream);
  // 2) merged prep + ELL fill
  prep_fill<<<FB + 768 + 2048, blk, 0, stream>>>(
      ei, deg, ell, E, FB, x, xb, (long long)Nn * 128 / 4,
      W1a, W2a, W1b, W2b, w1t, w2t, w3t, w4t);

  int lb = (Nn + 63) / 64;  // 782 blocks

  // 3-4) layer 0: unfused (cheap gather at full occupancy + dbuf MLP)
  agg_gather<16><<<2048, blk, 0, stream>>>(g0, xb, deg, ell, Nn);
  fused_mlp8<128, 256, true><<<lb, dim3(512), 0, stream>>>(
      g0, w1t, b1a, w2t, b2a, h, Nn);
  // 5) layer 1: fused (expensive gather overlapped with MLP)
  fused_layer<256, 128, false><<<lb, dim3(512), 0, stream>>>(
      h, deg, ell, w3t, b1b, w4t, b2b, out, Nn);
}

// Round 16
// 250.489 us; speedup vs baseline: 1.0191x; 1.0191x over previous
//
#include <hip/hip_runtime.h>

// ---------------------------------------------------------------------------
// GIN 2-layer forward. R26 = R24 verbatim (best measured: 249.9us).
// R25's pair-interleaved gather REVERTED: compiler kept VGPR=52 (refused to
// hold 16 loads in flight — same allocator defeat as R13/R14) and masked
// full batches added dup-edge loads (FETCH +2MB): net +5.4us/dispatch.
// HYBRID: layer 0 unfused (agg_gather<16> @ 8 blocks/CU + dbuf fused_mlp8);
// layer 1 fused (gather overlapped with MLP, -18us vs unfused).
// 5 dispatches: memset, prep_fill, agg16, mlp0, fused1.
// N=50000, E=600000, dims 128->256->256->256->128.
// ---------------------------------------------------------------------------

typedef __bf16 bf16x8 __attribute__((ext_vector_type(8)));
typedef float f32x4 __attribute__((ext_vector_type(4)));
typedef float f32x2 __attribute__((ext_vector_type(2)));
typedef unsigned short u16x4 __attribute__((ext_vector_type(4)));
typedef unsigned short u16x8 __attribute__((ext_vector_type(8)));
typedef unsigned int uint32;
typedef uint32 u32x4 __attribute__((ext_vector_type(4)));

#define MAXDEG 48

__device__ __forceinline__ unsigned short f2bf(float f) {
  uint32 u = __builtin_bit_cast(uint32, f);
  u += 0x7FFFu + ((u >> 16) & 1u);  // RNE
  return (unsigned short)(u >> 16);
}
// two bf16 (packed in a u32) -> two f32: lo via shift, hi via mask (1 instr each)
__device__ __forceinline__ f32x2 bfpair(uint32 w) {
  f32x2 r;
  r.x = __builtin_bit_cast(float, w << 16);
  r.y = __builtin_bit_cast(float, w & 0xFFFF0000u);
  return r;
}

#define G2L16(gp, lp)                                                        \
  __builtin_amdgcn_global_load_lds(                                          \
      (const __attribute__((address_space(1))) void*)(gp),                   \
      (__attribute__((address_space(3))) void*)(lp), 16, 0, 0)

// raw barrier with compiler-level memory fences; data readiness enforced by
// the explicit vmcnt
#define BARRIER()                                                            \
  do {                                                                       \
    asm volatile("" ::: "memory");                                           \
    __builtin_amdgcn_s_barrier();                                            \
    asm volatile("" ::: "memory");                                           \
  } while (0)
#define VMCNT0() asm volatile("s_waitcnt vmcnt(0)" ::: "memory")

// ---------------- merged prep + ELL fill (R21) ------------------------------
__global__ __launch_bounds__(256) void prep_fill(
    const int* __restrict__ eidx, int* __restrict__ deg, int* __restrict__ ell,
    int E, int FB,
    const float* __restrict__ x, unsigned short* __restrict__ xb, long long n4,
    const float* __restrict__ W1a, const float* __restrict__ W2a,
    const float* __restrict__ W1b, const float* __restrict__ W2b,
    unsigned short* __restrict__ w1t, unsigned short* __restrict__ w2t,
    unsigned short* __restrict__ w3t, unsigned short* __restrict__ w4t) {
  int b = blockIdx.x;
  int t = threadIdx.x;
  if (b < FB) {
    int e = b * 256 + t;
    if (e < E) {
      int s = eidx[e];
      int d = eidx[e + E];
      int c = atomicAdd(&deg[d], 1);
      if (c < MAXDEG) ell[d * MAXDEG + c] = s;
    }
  } else if (b < FB + 768) {
    int i = (b - FB) * 256 + t;  // 0..196607
    const float* W;
    unsigned short* WT;
    int K, N, j;
    if (i < 32768) {            // W1a: 128x256
      W = W1a; WT = w1t; K = 128; N = 256; j = i;
    } else if (i < 98304) {     // W2a: 256x256
      W = W2a; WT = w2t; K = 256; N = 256; j = i - 32768;
    } else if (i < 163840) {    // W1b: 256x256
      W = W1b; WT = w3t; K = 256; N = 256; j = i - 98304;
    } else {                    // W2b: 256x128
      W = W2b; WT = w4t; K = 256; N = 128; j = i - 163840;
    }
    int k = j / N, n = j - k * N;
    WT[n * K + k] = f2bf(W[j]);
  } else {
    long long i = (long long)(b - FB - 768) * 256 + t;
    long long stride = (long long)(gridDim.x - FB - 768) * 256;
    for (; i < n4; i += stride) {
      float4 v = ((const float4*)x)[i];
      u16x4 o;
      o.x = f2bf(v.x); o.y = f2bf(v.y); o.z = f2bf(v.z); o.w = f2bf(v.w);
      ((u16x4*)xb)[i] = o;
    }
  }
}

// ------------------------- aggregation (ELL, R19) ---------------------------
template <int GRP>  // D = GRP*8 dims: GRP=16 -> D=128
__global__ __launch_bounds__(256) void agg_gather(
    unsigned short* __restrict__ out, const unsigned short* __restrict__ src,
    const int* __restrict__ degv, const int* __restrict__ ell, int Nn) {
  constexpr int RS = GRP * 8;        // row stride in shorts (= D)
  constexpr int GPB = 256 / GRP;     // node-groups per block
  const int gid = threadIdx.x / GRP;
  const int gl  = threadIdx.x % GRP;
  const unsigned short* sp = src + gl * 8;
  const int stride = gridDim.x * GPB;
  for (int node = blockIdx.x * GPB + gid; node < Nn; node += stride) {
    const int beg = node * MAXDEG;
    int deg = degv[node];
    if (deg > MAXDEG) deg = MAXDEG;
    f32x2 acc[4];
    {  // self row ((1+eps)*x with eps=0)
      u32x4 w = *(const u32x4*)(sp + (size_t)node * RS);
#pragma unroll
      for (int k = 0; k < 4; ++k) acc[k] = bfpair(w[k]);
    }
    int j = 0;
    for (; j + 8 <= deg; j += 8) {  // full batches: no masking
      int idx[8];
#pragma unroll
      for (int u = 0; u < 8; ++u) idx[u] = ell[beg + j + u];
#pragma unroll
      for (int u = 0; u < 8; ++u) {
        u32x4 w = *(const u32x4*)(sp + (size_t)idx[u] * RS);
#pragma unroll
        for (int k = 0; k < 4; ++k) acc[k] += bfpair(w[k]);
      }
    }
    if (j < deg) {  // masked tail
#pragma unroll
      for (int u = 0; u < 8; ++u) {
        int jj = j + u;
        int e = beg + (jj < deg ? jj : deg - 1);
        float sel = (jj < deg) ? 1.f : 0.f;
        f32x2 fs = {sel, sel};
        int rv = ell[e];
        u32x4 w = *(const u32x4*)(sp + (size_t)rv * RS);
#pragma unroll
        for (int k = 0; k < 4; ++k) acc[k] += bfpair(w[k]) * fs;
      }
    }
    u16x8 o;
#pragma unroll
    for (int k = 0; k < 4; ++k) {
      o[2 * k] = f2bf(acc[k].x);
      o[2 * k + 1] = f2bf(acc[k].y);
    }
    *(u16x8*)(out + (size_t)node * RS + gl * 8) = o;
  }
}

// ------------- fused MLP, 8 waves, 2-phase dbuf pipeline (R20) ---------------
template <int K1, int N2, bool OUT_BF16>
__global__ __launch_bounds__(512) void fused_mlp8(
    const unsigned short* __restrict__ A,
    const unsigned short* __restrict__ BT1, const float* __restrict__ b1,
    const unsigned short* __restrict__ BT2, const float* __restrict__ b2,
    void* __restrict__ Cout, int M) {
  __shared__ unsigned short As[2][64 * 32];    // 8 KB
  __shared__ unsigned short Bs[2][256 * 32];   // 32 KB
  __shared__ unsigned short Ts[64 * 264];      // 33.8 KB
  const int tid = threadIdx.x;
  const int wave = tid >> 6, lane = tid & 63;
  const int quad = lane >> 4, l16 = lane & 15;
  const int rowBase = blockIdx.x * 64;

#define STAGE1(buf, kk)                                                      \
  for (int c = tid; c < 1280; c += 512) {                                    \
    if (c < 256) {                                                           \
      int r = rowBase + (c >> 2);                                            \
      if (r > M - 1) r = M - 1;                                              \
      G2L16(A + (long long)r * K1 + (kk) + (c & 3) * 8, As[buf] + c * 8);    \
    } else {                                                                 \
      int bb = c - 256;                                                      \
      G2L16(BT1 + (long long)(bb >> 2) * K1 + (kk) + (bb & 3) * 8,           \
            Bs[buf] + bb * 8);                                               \
    }                                                                        \
  }

  // ---- stage 1: T = relu(A @ W1 + b1); wave owns cols wave*32..+31 ----
  constexpr int nk1 = K1 / 32;
  f32x4 acc[4][2] = {};
  int cur = 0;
  STAGE1(0, 0);
  VMCNT0();
  BARRIER();
  for (int t = 0; t < nk1; ++t) {
    if (t + 1 < nk1) STAGE1(cur ^ 1, (t + 1) * 32);
    bf16x8 af[4], bfr[2];
#pragma unroll
    for (int mi = 0; mi < 4; ++mi)
      af[mi] = *(const bf16x8*)(As[cur] + (mi * 16 + l16) * 32 + quad * 8);
#pragma unroll
    for (int ni = 0; ni < 2; ++ni)
      bfr[ni] = *(const bf16x8*)(Bs[cur] + (wave * 32 + ni * 16 + l16) * 32 + quad * 8);
#pragma unroll
    for (int mi = 0; mi < 4; ++mi)
#pragma unroll
      for (int ni = 0; ni < 2; ++ni)
        acc[mi][ni] = __builtin_amdgcn_mfma_f32_16x16x32_bf16(
            af[mi], bfr[ni], acc[mi][ni], 0, 0, 0);
    VMCNT0();
    BARRIER();
    cur ^= 1;
  }
#pragma unroll
  for (int ni = 0; ni < 2; ++ni) {
    int col = wave * 32 + ni * 16 + l16;
    float bv = b1[col];
#pragma unroll
    for (int mi = 0; mi < 4; ++mi)
#pragma unroll
      for (int r = 0; r < 4; ++r) {
        int row = mi * 16 + quad * 4 + r;
        Ts[row * 264 + col] = f2bf(fmaxf(acc[mi][ni][r] + bv, 0.f));
      }
  }
  __syncthreads();

  // ---- stage 2: C = T @ W2 + b2; wave owns cols wave*(N2/8).. ----
  constexpr int NW2 = N2 / 8;
  constexpr int NI2 = NW2 / 16;
  constexpr int NCH2 = N2 * 4;

#define STAGE2(buf, kk)                                                      \
  for (int c = tid; c < NCH2; c += 512)                                      \
    G2L16(BT2 + (long long)(c >> 2) * 256 + (kk) + (c & 3) * 8,              \
          Bs[buf] + c * 8);

  f32x4 acc2[4][NI2] = {};
  cur = 0;
  STAGE2(0, 0);
  VMCNT0();
  BARRIER();
  for (int t = 0; t < 8; ++t) {
    int k2 = t * 32;
    if (t + 1 < 8) STAGE2(cur ^ 1, k2 + 32);
    bf16x8 af[4], bfr[NI2];
#pragma unroll
    for (int mi = 0; mi < 4; ++mi)
      af[mi] = *(const bf16x8*)(Ts + (mi * 16 + l16) * 264 + k2 + quad * 8);
#pragma unroll
    for (int ni = 0; ni < NI2; ++ni)
      bfr[ni] = *(const bf16x8*)(Bs[cur] + (wave * NW2 + ni * 16 + l16) * 32 + quad * 8);
#pragma unroll
    for (int mi = 0; mi < 4; ++mi)
#pragma unroll
      for (int ni = 0; ni < NI2; ++ni)
        acc2[mi][ni] = __builtin_amdgcn_mfma_f32_16x16x32_bf16(
            af[mi], bfr[ni], acc2[mi][ni], 0, 0, 0);
    VMCNT0();
    BARRIER();
    cur ^= 1;
  }
#pragma unroll
  for (int ni = 0; ni < NI2; ++ni) {
    int col = wave * NW2 + ni * 16 + l16;
    float bv = b2[col];
#pragma unroll
    for (int mi = 0; mi < 4; ++mi)
#pragma unroll
      for (int r = 0; r < 4; ++r) {
        int row = rowBase + mi * 16 + quad * 4 + r;
        if (row < M) {
          float o = acc2[mi][ni][r] + bv;
          if (OUT_BF16)
            ((unsigned short*)Cout)[(long long)row * N2 + col] = f2bf(fmaxf(o, 0.f));
          else
            ((float*)Cout)[(long long)row * N2 + col] = o;
        }
      }
  }
#undef STAGE1
#undef STAGE2
}

// ---------------- fused layer: gather + 2-stage MLP (R22 verbatim) ----------
template <int K1, int N2, bool OUT_BF16>
__global__ __launch_bounds__(512) void fused_layer(
    const unsigned short* __restrict__ src,   // gather table, row stride K1
    const int* __restrict__ degv, const int* __restrict__ ell,
    const unsigned short* __restrict__ BT1, const float* __restrict__ b1,
    const unsigned short* __restrict__ BT2, const float* __restrict__ b2,
    void* __restrict__ Cout, int Nn) {
  constexpr int GRP = K1 / 8;
  __shared__ unsigned short Ash[64 * 264];     // A-tile, then Ts (33.8 KB)
  __shared__ unsigned short Bs[2][256 * 32];   // 32 KB dbuf
  const int tid = threadIdx.x;
  const int wave = tid >> 6, lane = tid & 63;
  const int quad = lane >> 4, l16 = lane & 15;
  const int rowBase = blockIdx.x * 64;

#define STAGE1B(buf, kk)                                                     \
  for (int c = tid; c < 1024; c += 512)                                      \
    G2L16(BT1 + (long long)(c >> 2) * K1 + (kk) + (c & 3) * 8,               \
          Bs[buf] + c * 8);
#define STAGE2B(buf, kk)                                                     \
  for (int c = tid; c < N2 * 4; c += 512)                                    \
    G2L16(BT2 + (long long)(c >> 2) * 256 + (kk) + (c & 3) * 8,              \
          Bs[buf] + c * 8);

  // prologue: first B-tile flies under the gather
  STAGE1B(0, 0);

  // ---- phase A: gather this block's 64 rows into Ash ----
  {
    constexpr int NPG = 64 * GRP / 512;  // nodes per lane-group
    const int gid = tid / GRP, gl = tid % GRP;
    const unsigned short* sp = src + gl * 8;
#pragma unroll
    for (int nn = 0; nn < NPG; ++nn) {
      const int lrow = gid * NPG + nn;
      int node = rowBase + lrow;
      if (node > Nn - 1) node = Nn - 1;  // tail rows duplicate; stores guarded
      const int beg = node * MAXDEG;
      int deg = degv[node];
      if (deg > MAXDEG) deg = MAXDEG;
      f32x2 acc[4];
      {  // self row ((1+eps)*x with eps=0)
        u32x4 w = *(const u32x4*)(sp + (size_t)node * K1);
#pragma unroll
        for (int k = 0; k < 4; ++k) acc[k] = bfpair(w[k]);
      }
      int j = 0;
      for (; j + 8 <= deg; j += 8) {  // full batches: no masking
        int idx[8];
#pragma unroll
        for (int u = 0; u < 8; ++u) idx[u] = ell[beg + j + u];
#pragma unroll
        for (int u = 0; u < 8; ++u) {
          u32x4 w = *(const u32x4*)(sp + (size_t)idx[u] * K1);
#pragma unroll
          for (int k = 0; k < 4; ++k) acc[k] += bfpair(w[k]);
        }
      }
      if (j < deg) {  // masked tail
#pragma unroll
        for (int u = 0; u < 8; ++u) {
          int jj = j + u;
          int e = beg + (jj < deg ? jj : deg - 1);
          float sel = (jj < deg) ? 1.f : 0.f;
          f32x2 fs = {sel, sel};
          int rv = ell[e];
          u32x4 w = *(const u32x4*)(sp + (size_t)rv * K1);
#pragma unroll
          for (int k = 0; k < 4; ++k) acc[k] += bfpair(w[k]) * fs;
        }
      }
      u16x8 o;
#pragma unroll
      for (int k = 0; k < 4; ++k) {
        o[2 * k] = f2bf(acc[k].x);
        o[2 * k + 1] = f2bf(acc[k].y);
      }
      *(u16x8*)(Ash + lrow * 264 + gl * 8) = o;
    }
  }
  __syncthreads();  // gather ds_writes + STAGE1B(0) drained

  // ---- stage 1: T = relu(A @ W1 + b1); wave owns cols wave*32..+31 ----
  constexpr int nk1 = K1 / 32;
  f32x4 acc1[4][2] = {};
  int cur = 0;
  for (int t = 0; t < nk1; ++t) {
    if (t + 1 < nk1) STAGE1B(cur ^ 1, (t + 1) * 32);
    bf16x8 af[4], bfr[2];
#pragma unroll
    for (int mi = 0; mi < 4; ++mi)
      af[mi] = *(const bf16x8*)(Ash + (mi * 16 + l16) * 264 + t * 32 + quad * 8);
#pragma unroll
    for (int ni = 0; ni < 2; ++ni)
      bfr[ni] = *(const bf16x8*)(Bs[cur] + (wave * 32 + ni * 16 + l16) * 32 + quad * 8);
#pragma unroll
    for (int mi = 0; mi < 4; ++mi)
#pragma unroll
      for (int ni = 0; ni < 2; ++ni)
        acc1[mi][ni] = __builtin_amdgcn_mfma_f32_16x16x32_bf16(
            af[mi], bfr[ni], acc1[mi][ni], 0, 0, 0);
    VMCNT0();
    BARRIER();
    cur ^= 1;
  }

  // stage-2 prologue hides under the Ts write
  STAGE2B(0, 0);
#pragma unroll
  for (int ni = 0; ni < 2; ++ni) {
    int col = wave * 32 + ni * 16 + l16;
    float bv = b1[col];
#pragma unroll
    for (int mi = 0; mi < 4; ++mi)
#pragma unroll
      for (int r = 0; r < 4; ++r) {
        int row = mi * 16 + quad * 4 + r;
        Ash[row * 264 + col] = f2bf(fmaxf(acc1[mi][ni][r] + bv, 0.f));
      }
  }
  __syncthreads();  // Ts writes + STAGE2B(0) drained

  // ---- stage 2: C = T @ W2 + b2; wave owns cols wave*(N2/8).. ----
  constexpr int NW2 = N2 / 8;
  constexpr int NI2 = NW2 / 16;
  f32x4 acc2[4][NI2] = {};
  cur = 0;
  for (int t = 0; t < 8; ++t) {
    int k2 = t * 32;
    if (t + 1 < 8) STAGE2B(cur ^ 1, k2 + 32);
    bf16x8 af[4], bfr[NI2];
#pragma unroll
    for (int mi = 0; mi < 4; ++mi)
      af[mi] = *(const bf16x8*)(Ash + (mi * 16 + l16) * 264 + k2 + quad * 8);
#pragma unroll
    for (int ni = 0; ni < NI2; ++ni)
      bfr[ni] = *(const bf16x8*)(Bs[cur] + (wave * NW2 + ni * 16 + l16) * 32 + quad * 8);
#pragma unroll
    for (int mi = 0; mi < 4; ++mi)
#pragma unroll
      for (int ni = 0; ni < NI2; ++ni)
        acc2[mi][ni] = __builtin_amdgcn_mfma_f32_16x16x32_bf16(
            af[mi], bfr[ni], acc2[mi][ni], 0, 0, 0);
    VMCNT0();
    BARRIER();
    cur ^= 1;
  }
#pragma unroll
  for (int ni = 0; ni < NI2; ++ni) {
    int col = wave * NW2 + ni * 16 + l16;
    float bv = b2[col];
#pragma unroll
    for (int mi = 0; mi < 4; ++mi)
#pragma unroll
      for (int r = 0; r < 4; ++r) {
        int row = rowBase + mi * 16 + quad * 4 + r;
        if (row < Nn) {
          float o = acc2[mi][ni][r] + bv;
          if (OUT_BF16)
            ((unsigned short*)Cout)[(long long)row * N2 + col] = f2bf(fmaxf(o, 0.f));
          else
            ((float*)Cout)[(long long)row * N2 + col] = o;
        }
      }
  }
#undef STAGE1B
#undef STAGE2B
}

// ---------------------------------------------------------------------------
extern "C" void kernel_launch(void* const* d_in, const int* in_sizes, int n_in,
                              void* d_out, int out_size, void* d_ws, size_t ws_size,
                              hipStream_t stream) {
  const float* x   = (const float*)d_in[0];
  const float* W1a = (const float*)d_in[1];
  const float* b1a = (const float*)d_in[2];
  const float* W2a = (const float*)d_in[3];
  const float* b2a = (const float*)d_in[4];
  const float* W1b = (const float*)d_in[5];
  const float* b1b = (const float*)d_in[6];
  const float* W2b = (const float*)d_in[7];
  const float* b2b = (const float*)d_in[8];
  const int*   ei  = (const int*)d_in[9];  // [2,E]: row0=src, row1=dst

  const int Nn = in_sizes[0] / 128;  // 50000
  const int E  = in_sizes[9] / 2;    // 600000
  float* out = (float*)d_out;

  // workspace
  unsigned short* h   = (unsigned short*)d_ws;     // N*256 bf16
  unsigned short* g0  = h  + (size_t)Nn * 256;     // N*128 (layer-0 agg out)
  unsigned short* xb  = g0 + (size_t)Nn * 128;     // N*128
  unsigned short* w1t = xb + (size_t)Nn * 128;     // 256*128
  unsigned short* w2t = w1t + 256 * 128;           // 256*256
  unsigned short* w3t = w2t + 256 * 256;           // 256*256
  unsigned short* w4t = w3t + 256 * 256;           // 128*256
  int* deg  = (int*)(w4t + 128 * 256);             // Nn (zeroed by memset)
  int* ell  = deg + Nn;                            // Nn*MAXDEG

  dim3 blk(256);
  const int FB = (E + 255) / 256;  // 2344 fill blocks

  // 1) zero deg (stream-ordered, graph-capturable)
  hipMemsetAsync(deg, 0, (size_t)Nn * sizeof(int), stream);
  // 2) merged prep + ELL fill
  prep_fill<<<FB + 768 + 2048, blk, 0, stream>>>(
      ei, deg, ell, E, FB, x, xb, (long long)Nn * 128 / 4,
      W1a, W2a, W1b, W2b, w1t, w2t, w3t, w4t);

  int lb = (Nn + 63) / 64;  // 782 blocks

  // 3-4) layer 0: unfused (cheap gather at full occupancy + dbuf MLP)
  agg_gather<16><<<2048, blk, 0, stream>>>(g0, xb, deg, ell, Nn);
  fused_mlp8<128, 256, true><<<lb, dim3(512), 0, stream>>>(
      g0, w1t, b1a, w2t, b2a, h, Nn);
  // 5) layer 1: fused (expensive gather overlapped with MLP)
  fused_layer<256, 128, false><<<lb, dim3(512), 0, stream>>>(
      h, deg, ell, w3t, b1b, w4t, b2b, out, Nn);
}